// Round 4
// baseline (34.217 us; speedup 1.0000x reference)
//
#include <hip/hip_runtime.h>
#include <math.h>

#define NG    512
#define IMG_W 256
#define IMG_H 192

#define NEAR_P    0.1f
#define FAR_P     100.0f
#define ALPHA_MAX 0.99f

#define PIX     64     // pixels per render block (one row strip)
#define CHUNKS  4
#define TPB     256    // PIX * CHUNKS

// ws layout (float4 units), all depth-sorted by k1:
//  [3*i+0] = { A=-0.5*conic_a, B=-conic_b, C=-0.5*conic_c, mx }
//  [3*i+1] = { my (1e30 if invis), op (0 if invis), col_r, col_g }
//  [3*i+2] = { col_b, unused, unused, unused }
//  [3*NG+i] = { mx, my (1e30 if invis), r5 (0 if invis), 0 }   // cull record

// ---------------- k1: preprocess + global stable depth rank-sort ----------
__global__ __launch_bounds__(NG) void gs_prep(
    const float* __restrict__ pos,
    const float* __restrict__ scl,
    const float* __restrict__ rot,
    const float* __restrict__ opa,
    const float* __restrict__ col,
    const float* __restrict__ vm,
    const int*   __restrict__ fov,
    float4* __restrict__ ws)
{
    __shared__ float4 s_key4[NG/4];
    float* s_key = (float*)s_key4;

    const int g = threadIdx.x;

    // ---- quaternion -> rotation (rsqrt normalize) ----
    float qw = rot[g*4+0], qx = rot[g*4+1], qy = rot[g*4+2], qz = rot[g*4+3];
    float rn = __frsqrt_rn(qw*qw + qx*qx + qy*qy + qz*qz);
    qw *= rn; qx *= rn; qy *= rn; qz *= rn;
    float R00 = 1.f - 2.f*(qy*qy + qz*qz);
    float R01 = 2.f*(qx*qy - qw*qz);
    float R02 = 2.f*(qx*qz + qw*qy);
    float R10 = 2.f*(qx*qy + qw*qz);
    float R11 = 1.f - 2.f*(qx*qx + qz*qz);
    float R12 = 2.f*(qy*qz - qw*qx);
    float R20 = 2.f*(qx*qz - qw*qy);
    float R21 = 2.f*(qy*qz + qw*qx);
    float R22 = 1.f - 2.f*(qx*qx + qy*qy);

    // ---- cov3d = R diag(s^2) R^T ----
    float s0 = scl[g*3+0], s1 = scl[g*3+1], s2 = scl[g*3+2];
    float q0 = s0*s0, q1 = s1*s1, q2 = s2*s2;
    float C00 = R00*R00*q0 + R01*R01*q1 + R02*R02*q2;
    float C01 = R00*R10*q0 + R01*R11*q1 + R02*R12*q2;
    float C02 = R00*R20*q0 + R01*R21*q1 + R02*R22*q2;
    float C11 = R10*R10*q0 + R11*R11*q1 + R12*R12*q2;
    float C12 = R10*R20*q0 + R11*R21*q1 + R12*R22*q2;
    float C22 = R20*R20*q0 + R21*R21*q1 + R22*R22*q2;

    // ---- camera transform ----
    float W00 = vm[0],  W01 = vm[1],  W02 = vm[2],  t0 = vm[3];
    float W10 = vm[4],  W11 = vm[5],  W12 = vm[6],  t1 = vm[7];
    float W20 = vm[8],  W21 = vm[9],  W22 = vm[10], t2 = vm[11];
    float px = pos[g*3+0], py = pos[g*3+1], pz = pos[g*3+2];
    float X = W00*px + W01*py + W02*pz + t0;
    float Y = W10*px + W11*py + W12*pz + t1;
    float Z = W20*px + W21*py + W22*pz + t2;

    float depth = Z;
    float zs = fmaxf(depth, NEAR_P);

    const float fx = (float)IMG_W /
        (2.0f * tanf((float)fov[0] * (float)(M_PI / 180.0) * 0.5f));

    float rz   = __fdividef(1.0f, zs);
    float fxrz = fx * rz;

    float mx = fxrz * X + (float)IMG_W * 0.5f;
    float my = (float)IMG_H * 0.5f - fxrz * Y;

    // ---- T = J @ Wr (2x3); j00=j11=fxrz ----
    float j02 = -fxrz * X * rz;
    float j12 = -fxrz * Y * rz;
    float T00 = fxrz*W00 + j02*W20;
    float T01 = fxrz*W01 + j02*W21;
    float T02 = fxrz*W02 + j02*W22;
    float T10 = fxrz*W10 + j12*W20;
    float T11 = fxrz*W11 + j12*W21;
    float T12 = fxrz*W12 + j12*W22;

    // ---- cov2d = T C T^T ----
    float u0 = C00*T00 + C01*T01 + C02*T02;
    float u1 = C01*T00 + C11*T01 + C12*T02;
    float u2 = C02*T00 + C12*T01 + C22*T02;
    float v0 = C00*T10 + C01*T11 + C02*T12;
    float v1 = C01*T10 + C11*T11 + C12*T12;
    float v2 = C02*T10 + C12*T11 + C22*T12;
    float a    = T00*u0 + T01*u1 + T02*u2;
    float bcov = 0.5f * ((T00*v0 + T01*v1 + T02*v2) + (T10*u0 + T11*u1 + T12*u2));
    float c    = T10*v0 + T11*v1 + T12*v2;

    // ---- eigen clamp ----
    float mean_e = 0.5f * (a + c);
    float disc = sqrtf(fmaxf(0.25f*(a - c)*(a - c) + bcov*bcov, 0.0f));
    float min_eig = mean_e - disc;
    float eps = (min_eig <= 0.0f) ? (fabsf(min_eig) + 1e-6f) : 0.0f;
    a += eps; c += eps;
    float max_eig = mean_e + eps + disc;
    float radii = ceilf(3.0f * sqrtf(fmaxf(max_eig, 1e-6f)));

    bool visible = (depth > NEAR_P) && (depth < FAR_P) && (radii > 0.0f);

    float det  = fmaxf(a*c - bcov*bcov, 1e-12f);
    float rdet = __fdividef(1.0f, det);
    float ca = c * rdet, cbv = -bcov * rdet, cc = a * rdet;
    float op = __fdividef(1.0f, 1.0f + __expf(-opa[g]));
    float r5 = 5.0f * sqrtf(fmaxf(max_eig, 1e-6f));

    float key = visible ? -depth : INFINITY;
    s_key[g] = key;
    __syncthreads();

    // ---- stable rank: r = #{ j : key_j < key_g or (==, j<g) } ----
    int r = 0;
    #pragma unroll 4
    for (int j4 = 0; j4 < NG/4; ++j4) {
        float4 kv = s_key4[j4];
        int j = 4*j4;
        r += (int)((kv.x < key) | ((kv.x == key) & (j     < g)));
        r += (int)((kv.y < key) | ((kv.y == key) & (j + 1 < g)));
        r += (int)((kv.z < key) | ((kv.z == key) & (j + 2 < g)));
        r += (int)((kv.w < key) | ((kv.w == key) & (j + 3 < g)));
    }

    float myc = visible ? my : 1e30f;
    ws[3*r+0] = make_float4(-0.5f*ca, -cbv, -0.5f*cc, mx);
    ws[3*r+1] = make_float4(myc, visible ? op : 0.0f, col[g*3+0], col[g*3+1]);
    ws[3*r+2] = make_float4(col[g*3+2], 0.0f, 0.0f, 0.0f);
    ws[3*NG + r] = make_float4(mx, myc, visible ? r5 : 0.0f, 0.0f);
}

// ---------------- k2: cull + order-preserving compaction + composite ------
__global__ __launch_bounds__(TPB) void gs_render(
    const float4* __restrict__ ws,
    const float* __restrict__ bg,
    float* __restrict__ out)
{
    __shared__ float4 sg[NG*3];                 // 24 KB sorted records
    __shared__ float4 s_cull[NG];               // 8 KB  {mx,my,r5,-}
    __shared__ unsigned short s_list[NG];       // compacted (depth-ordered) ids
    __shared__ int    s_wtot[4], s_woff[4], s_M;
    __shared__ float4 s_part[CHUNKS][PIX];
    __shared__ float  s_out[PIX*3];

    const int tid = threadIdx.x;

    for (int i = tid; i < NG*3; i += TPB) sg[i] = ws[i];
    for (int i = tid; i < NG;   i += TPB) s_cull[i] = ws[3*NG + i];
    __syncthreads();

    const int   b   = blockIdx.x;
    const float yf  = (float)(b >> 2);
    const float x0f = (float)((b & 3) * PIX);

    // ---- 5-sigma strip cull + ballot compaction (keeps depth order) ----
    const int g0 = 2*tid, g1 = g0 + 1;
    float4 cr0 = s_cull[g0];
    float4 cr1 = s_cull[g1];
    bool p0 = (fabsf(cr0.y - yf) <= cr0.z) &
              (cr0.x >= x0f - cr0.z) & (cr0.x <= x0f + 63.0f + cr0.z);
    bool p1 = (fabsf(cr1.y - yf) <= cr1.z) &
              (cr1.x >= x0f - cr1.z) & (cr1.x <= x0f + 63.0f + cr1.z);

    unsigned long long m0 = __ballot(p0);
    unsigned long long m1 = __ballot(p1);
    const int lane = tid & 63;
    const int wv   = tid >> 6;
    unsigned long long lt = (1ull << lane) - 1ull;

    if (lane == 0) s_wtot[wv] = __popcll(m0) + __popcll(m1);
    __syncthreads();
    if (tid == 0) {
        int acc = 0;
        for (int i = 0; i < 4; ++i) { s_woff[i] = acc; acc += s_wtot[i]; }
        s_M = acc;
    }
    __syncthreads();
    int basep = s_woff[wv] + __popcll(m0 & lt) + __popcll(m1 & lt);
    if (p0) s_list[basep] = (unsigned short)g0;
    if (p1) s_list[basep + (p0 ? 1 : 0)] = (unsigned short)g1;
    __syncthreads();

    // ---- chunked composite over depth-ordered survivors ----
    const int M  = s_M;
    const int qn = (M + CHUNKS - 1) / CHUNKS;
    const int lpix  = tid & 63;
    const int chunk = tid >> 6;
    int start = chunk * qn; if (start > M) start = M;
    int end   = start + qn; if (end > M) end = M;

    const float fxp = x0f + (float)lpix;

    float Tr = 1.0f, ar = 0.0f, ag = 0.0f, abv = 0.0f;
    for (int i = start; i < end; ++i) {
        int gi = s_list[i];
        float4 r0 = sg[3*gi+0];
        float4 r1 = sg[3*gi+1];
        float  bc = sg[3*gi+2].x;
        float dx = fxp - r0.w;
        float dy = yf  - r1.x;
        float qv = (r0.x*dx)*dx + (r0.y*dx)*dy + (r0.z*dy)*dy; // = -0.5*q
        float G = __expf(fminf(qv, 0.0f));
        float alpha = fminf(r1.y * G, ALPHA_MAX);
        float wgt = alpha * Tr;
        ar  += wgt * r1.z;
        ag  += wgt * r1.w;
        abv += wgt * bc;
        Tr  *= (1.0f - alpha);
    }
    s_part[chunk][lpix] = make_float4(ar, ag, abv, Tr);
    __syncthreads();

    if (chunk == 0) {
        float4 c0 = s_part[0][lpix], c1 = s_part[1][lpix];
        float4 c2 = s_part[2][lpix], c3 = s_part[3][lpix];
        float T0 = c0.w, T01 = T0*c1.w, T012 = T01*c2.w, Tall = T012*c3.w;
        float r  = c0.x + T0*c1.x + T01*c2.x + T012*c3.x;
        float gc = c0.y + T0*c1.y + T01*c2.y + T012*c3.y;
        float bb = c0.z + T0*c1.z + T01*c2.z + T012*c3.z;
        s_out[3*lpix+0] = r  + Tall * bg[0];
        s_out[3*lpix+1] = gc + Tall * bg[1];
        s_out[3*lpix+2] = bb + Tall * bg[2];
    }
    __syncthreads();
    if (tid < PIX*3)
        out[b * (PIX*3) + tid] = s_out[tid];
}

extern "C" void kernel_launch(void* const* d_in, const int* in_sizes, int n_in,
                              void* d_out, int out_size, void* d_ws, size_t ws_size,
                              hipStream_t stream) {
    const float* pos = (const float*)d_in[0];
    const float* scl = (const float*)d_in[1];
    const float* rot = (const float*)d_in[2];
    const float* opa = (const float*)d_in[3];
    const float* col = (const float*)d_in[4];
    const float* vm  = (const float*)d_in[5];
    const float* bgp = (const float*)d_in[6];
    const int*   fov = (const int*)d_in[7];

    float4* ws  = (float4*)d_ws;
    float*  out = (float*)d_out;

    gs_prep<<<1, NG, 0, stream>>>(pos, scl, rot, opa, col, vm, fov, ws);
    gs_render<<<(IMG_H * IMG_W) / PIX, TPB, 0, stream>>>(ws, bgp, out);
}

// Round 5
// 22.256 us; speedup vs baseline: 1.5374x; 1.5374x over previous
//
#include <hip/hip_runtime.h>
#include <math.h>

#define NG    512
#define IMG_W 256
#define IMG_H 192

#define NEAR_P    0.1f
#define FAR_P     100.0f
#define ALPHA_MAX 0.99f

#define PIX     64     // pixels per block (one row strip)
#define CHUNKS  4
#define TPB     256    // PIX * CHUNKS

// One fused kernel (single dispatch): every block redundantly preprocesses
// all NG gaussians into LDS (fast-math), culls to its 64x1 strip, rank-sorts
// survivors by depth (stable == reference argsort restricted to survivors),
// then composites with a 4-way transmittance-split scan.

__global__ __launch_bounds__(TPB) void gs_fused(
    const float* __restrict__ pos,
    const float* __restrict__ scl,
    const float* __restrict__ rot,
    const float* __restrict__ opa,
    const float* __restrict__ col,
    const float* __restrict__ vm,
    const int*   __restrict__ fov,
    const float* __restrict__ bg,
    float* __restrict__ out)
{
    __shared__ float4 s_rec0[NG];            // A=-0.5ca, B=-cb, C=-0.5cc, mx
    __shared__ float4 s_rec1[NG];            // my, op(0 if invis), col_r, col_g
    __shared__ float  s_bcol[NG];            // col_b
    __shared__ float4 s_cull[NG];            // mx, my(1e30 invis), r5(0 invis), key
    __shared__ float  s_key2[NG];            // compacted keys
    __shared__ unsigned short s_list[NG];    // compacted ids (ascending id)
    __shared__ unsigned short s_order[NG];   // depth-ordered ids
    __shared__ int    s_wtot[4], s_woff[4], s_M;
    __shared__ float4 s_part[CHUNKS][PIX];
    __shared__ float  s_out[PIX*3];

    const int tid = threadIdx.x;

    const float fx = (float)IMG_W /
        (2.0f * __tanf((float)fov[0] * (float)(M_PI / 180.0) * 0.5f));

    const float W00 = vm[0],  W01 = vm[1],  W02 = vm[2],  t0 = vm[3];
    const float W10 = vm[4],  W11 = vm[5],  W12 = vm[6],  t1 = vm[7];
    const float W20 = vm[8],  W21 = vm[9],  W22 = vm[10], t2 = vm[11];

    // ---- per-gaussian preprocessing (2 per thread, fast-math) ----
    #pragma unroll
    for (int gg = 0; gg < 2; ++gg) {
        const int g = tid + gg * TPB;

        float qw = rot[g*4+0], qx = rot[g*4+1], qy = rot[g*4+2], qz = rot[g*4+3];
        float rn = __frsqrt_rn(qw*qw + qx*qx + qy*qy + qz*qz);
        qw *= rn; qx *= rn; qy *= rn; qz *= rn;
        float R00 = 1.f - 2.f*(qy*qy + qz*qz);
        float R01 = 2.f*(qx*qy - qw*qz);
        float R02 = 2.f*(qx*qz + qw*qy);
        float R10 = 2.f*(qx*qy + qw*qz);
        float R11 = 1.f - 2.f*(qx*qx + qz*qz);
        float R12 = 2.f*(qy*qz - qw*qx);
        float R20 = 2.f*(qx*qz - qw*qy);
        float R21 = 2.f*(qy*qz + qw*qx);
        float R22 = 1.f - 2.f*(qx*qx + qy*qy);

        float s0 = scl[g*3+0], s1 = scl[g*3+1], s2 = scl[g*3+2];
        float q0 = s0*s0, q1 = s1*s1, q2 = s2*s2;
        float C00 = R00*R00*q0 + R01*R01*q1 + R02*R02*q2;
        float C01 = R00*R10*q0 + R01*R11*q1 + R02*R12*q2;
        float C02 = R00*R20*q0 + R01*R21*q1 + R02*R22*q2;
        float C11 = R10*R10*q0 + R11*R11*q1 + R12*R12*q2;
        float C12 = R10*R20*q0 + R11*R21*q1 + R12*R22*q2;
        float C22 = R20*R20*q0 + R21*R21*q1 + R22*R22*q2;

        float px = pos[g*3+0], py = pos[g*3+1], pz = pos[g*3+2];
        float X = W00*px + W01*py + W02*pz + t0;
        float Y = W10*px + W11*py + W12*pz + t1;
        float Z = W20*px + W21*py + W22*pz + t2;

        float depth = Z;
        float zs = fmaxf(depth, NEAR_P);
        float rz = __fdividef(1.0f, zs);
        float fxrz = fx * rz;

        float mx = fxrz * X + (float)IMG_W * 0.5f;
        float my = (float)IMG_H * 0.5f - fxrz * Y;

        float j02 = -fxrz * X * rz;
        float j12 = -fxrz * Y * rz;
        float T00 = fxrz*W00 + j02*W20;
        float T01 = fxrz*W01 + j02*W21;
        float T02 = fxrz*W02 + j02*W22;
        float T10 = fxrz*W10 + j12*W20;
        float T11 = fxrz*W11 + j12*W21;
        float T12 = fxrz*W12 + j12*W22;

        float u0 = C00*T00 + C01*T01 + C02*T02;
        float u1 = C01*T00 + C11*T01 + C12*T02;
        float u2 = C02*T00 + C12*T01 + C22*T02;
        float v0 = C00*T10 + C01*T11 + C02*T12;
        float v1 = C01*T10 + C11*T11 + C12*T12;
        float v2 = C02*T10 + C12*T11 + C22*T12;
        float a    = T00*u0 + T01*u1 + T02*u2;
        float bcov = 0.5f * ((T00*v0 + T01*v1 + T02*v2) + (T10*u0 + T11*u1 + T12*u2));
        float c    = T10*v0 + T11*v1 + T12*v2;

        float mean_e = 0.5f * (a + c);
        float disc = sqrtf(fmaxf(0.25f*(a - c)*(a - c) + bcov*bcov, 0.0f));
        float min_eig = mean_e - disc;
        float eps = (min_eig <= 0.0f) ? (fabsf(min_eig) + 1e-6f) : 0.0f;
        a += eps; c += eps;
        float max_eig = mean_e + eps + disc;
        float radii = ceilf(3.0f * sqrtf(fmaxf(max_eig, 1e-6f)));

        bool visible = (depth > NEAR_P) && (depth < FAR_P) && (radii > 0.0f);

        float det  = fmaxf(a*c - bcov*bcov, 1e-12f);
        float rdet = __fdividef(1.0f, det);
        float ca = c * rdet, cbv = -bcov * rdet, cc = a * rdet;
        float op = __fdividef(1.0f, 1.0f + __expf(-opa[g]));
        float r5 = 5.0f * sqrtf(fmaxf(max_eig, 1e-6f));

        float myc = visible ? my : 1e30f;
        s_rec0[g] = make_float4(-0.5f*ca, -cbv, -0.5f*cc, mx);
        s_rec1[g] = make_float4(my, visible ? op : 0.0f, col[g*3+0], col[g*3+1]);
        s_bcol[g] = col[g*3+2];
        s_cull[g] = make_float4(mx, myc, visible ? r5 : 0.0f,
                                visible ? -depth : INFINITY);
    }
    __syncthreads();

    const int   b   = blockIdx.x;
    const float yf  = (float)(b >> 2);
    const float x0f = (float)((b & 3) * PIX);

    // ---- 5-sigma strip cull + order-preserving ballot compaction ----
    const int g0 = 2*tid, g1 = g0 + 1;
    float4 cr0 = s_cull[g0];
    float4 cr1 = s_cull[g1];
    bool p0 = (fabsf(cr0.y - yf) <= cr0.z) &
              (cr0.x >= x0f - cr0.z) & (cr0.x <= x0f + 63.0f + cr0.z);
    bool p1 = (fabsf(cr1.y - yf) <= cr1.z) &
              (cr1.x >= x0f - cr1.z) & (cr1.x <= x0f + 63.0f + cr1.z);

    unsigned long long m0 = __ballot(p0);
    unsigned long long m1 = __ballot(p1);
    const int lane = tid & 63;
    const int wv   = tid >> 6;
    unsigned long long lt = (1ull << lane) - 1ull;

    if (lane == 0) s_wtot[wv] = __popcll(m0) + __popcll(m1);
    __syncthreads();
    if (tid == 0) {
        int acc = 0;
        for (int i = 0; i < 4; ++i) { s_woff[i] = acc; acc += s_wtot[i]; }
        s_M = acc;
    }
    __syncthreads();
    int basep = s_woff[wv] + __popcll(m0 & lt) + __popcll(m1 & lt);
    if (p0) { s_list[basep] = (unsigned short)g0; s_key2[basep] = cr0.w; }
    if (p1) { int p = basep + (p0 ? 1 : 0);
              s_list[p] = (unsigned short)g1; s_key2[p] = cr1.w; }
    __syncthreads();

    // ---- rank-sort survivors by (key, list-pos) — stable depth order ----
    const int M = s_M;
    for (int t = tid; t < M; t += TPB) {
        float k = s_key2[t];
        int r = 0;
        for (int j = 0; j < M; ++j) {
            float kj = s_key2[j];
            r += (kj < k) || (kj == k && j < t);
        }
        s_order[r] = s_list[t];
    }
    __syncthreads();

    // ---- chunked composite ----
    const int qn = (M + CHUNKS - 1) / CHUNKS;
    const int lpix  = tid & 63;
    const int chunk = tid >> 6;
    int start = chunk * qn; if (start > M) start = M;
    int end   = start + qn; if (end > M) end = M;

    const float fxp = x0f + (float)lpix;

    float Tr = 1.0f, ar = 0.0f, ag = 0.0f, abv = 0.0f;
    for (int i = start; i < end; ++i) {
        int gi = s_order[i];
        float4 r0 = s_rec0[gi];
        float4 r1 = s_rec1[gi];
        float  bc = s_bcol[gi];
        float dx = fxp - r0.w;
        float dy = yf  - r1.x;
        float qv = (r0.x*dx)*dx + (r0.y*dx)*dy + (r0.z*dy)*dy; // = -0.5*q
        float G = __expf(fminf(qv, 0.0f));
        float alpha = fminf(r1.y * G, ALPHA_MAX);
        float wgt = alpha * Tr;
        ar  += wgt * r1.z;
        ag  += wgt * r1.w;
        abv += wgt * bc;
        Tr  *= (1.0f - alpha);
    }
    s_part[chunk][lpix] = make_float4(ar, ag, abv, Tr);
    __syncthreads();

    if (chunk == 0) {
        float4 c0 = s_part[0][lpix], c1 = s_part[1][lpix];
        float4 c2 = s_part[2][lpix], c3 = s_part[3][lpix];
        float T0 = c0.w, T01 = T0*c1.w, T012 = T01*c2.w, Tall = T012*c3.w;
        float r  = c0.x + T0*c1.x + T01*c2.x + T012*c3.x;
        float gc = c0.y + T0*c1.y + T01*c2.y + T012*c3.y;
        float bb = c0.z + T0*c1.z + T01*c2.z + T012*c3.z;
        s_out[3*lpix+0] = r  + Tall * bg[0];
        s_out[3*lpix+1] = gc + Tall * bg[1];
        s_out[3*lpix+2] = bb + Tall * bg[2];
    }
    __syncthreads();
    if (tid < PIX*3)
        out[b * (PIX*3) + tid] = s_out[tid];
}

extern "C" void kernel_launch(void* const* d_in, const int* in_sizes, int n_in,
                              void* d_out, int out_size, void* d_ws, size_t ws_size,
                              hipStream_t stream) {
    const float* pos = (const float*)d_in[0];
    const float* scl = (const float*)d_in[1];
    const float* rot = (const float*)d_in[2];
    const float* opa = (const float*)d_in[3];
    const float* col = (const float*)d_in[4];
    const float* vm  = (const float*)d_in[5];
    const float* bgp = (const float*)d_in[6];
    const int*   fov = (const int*)d_in[7];

    float* out = (float*)d_out;

    gs_fused<<<(IMG_H * IMG_W) / PIX, TPB, 0, stream>>>(
        pos, scl, rot, opa, col, vm, fov, bgp, out);
}

// Round 7
// 19.324 us; speedup vs baseline: 1.7707x; 1.1517x over previous
//
#include <hip/hip_runtime.h>
#include <math.h>

#define NG    512
#define IMG_W 256
#define IMG_H 192

#define NEAR_P    0.1f
#define FAR_P     100.0f
#define ALPHA_MAX 0.99f

#define PIX     64     // pixels per block (one row strip)
#define CHUNKS  4
#define TPB     256    // PIX * CHUNKS

#define CULL_K  4.25f  // cull radius in sigmas (dropped terms <= op*e^-9.03)

// Single fused dispatch. Per block (one 64x1 pixel strip):
//  P1  cheap phase, all NG: depth/mx/my + conservative radius bound
//      rb = K*sqrt(smax^2 * lmax(JJ^T)),  smax^2 = lmax(cov3d) exactly,
//      lmax(JJ^T) = (fx/z)^2*(1+Xr^2+Yr^2) exactly  (vm is a rotation)
//  P2  strip cull on the bound + order-preserving ballot compaction
//  P3  stable rank-sort of the M pre-survivors by depth (== reference
//      argsort restricted to survivors; ties by ascending gaussian id)
//  P4  full preprocess of sorted survivors in TWO half-passes (M may be
//      up to 512 > TPB!), exact K-sigma cull, running-offset compaction,
//      records written in depth order
//  P5  4-way transmittance-split composite, direct sequential record reads

__global__ __launch_bounds__(TPB) void gs_fused(
    const float* __restrict__ pos,
    const float* __restrict__ scl,
    const float* __restrict__ rot,
    const float* __restrict__ opa,
    const float* __restrict__ col,
    const float* __restrict__ vm,
    const int*   __restrict__ fov,
    const float* __restrict__ bg,
    float* __restrict__ out)
{
    __shared__ float4 s_cull[NG];              // mx, my(1e30 invis), rb, key
    __shared__ float4 s_key4[NG/4 + 1];        // compacted keys (+INF pad)
    __shared__ unsigned short s_list[NG];      // pre-survivors, ascending id
    __shared__ unsigned short s_order[NG];     // pre-survivors, depth order
    __shared__ float4 s_rec0[NG];              // depth-ordered: A,B,C,mx
    __shared__ float4 s_rec1[NG];              // my, op, col_r, col_g
    __shared__ float  s_bcol[NG];              // col_b
    __shared__ int    s_wtot[4], s_woff[4], s_M, s_Mf;
    __shared__ float4 s_part[CHUNKS][PIX];
    __shared__ float  s_out[PIX*3];

    float* s_key2 = (float*)s_key4;

    const int tid = threadIdx.x;

    const float fx = (float)IMG_W /
        (2.0f * __tanf((float)fov[0] * (float)(M_PI / 180.0) * 0.5f));

    const float W00 = vm[0],  W01 = vm[1],  W02 = vm[2],  t0 = vm[3];
    const float W10 = vm[4],  W11 = vm[5],  W12 = vm[6],  t1 = vm[7];
    const float W20 = vm[8],  W21 = vm[9],  W22 = vm[10], t2 = vm[11];

    const int   b   = blockIdx.x;
    const float yf  = (float)(b >> 2);
    const float x0f = (float)((b & 3) * PIX);

    // ---------------- P1: cheap phase (2 gaussians/thread) ----------------
    #pragma unroll
    for (int gg = 0; gg < 2; ++gg) {
        const int g = tid + gg * TPB;
        float px = pos[g*3+0], py = pos[g*3+1], pz = pos[g*3+2];
        float X = W00*px + W01*py + W02*pz + t0;
        float Y = W10*px + W11*py + W12*pz + t1;
        float Z = W20*px + W21*py + W22*pz + t2;

        float depth = Z;
        float zs = fmaxf(depth, NEAR_P);
        float rz = __fdividef(1.0f, zs);
        float fxrz = fx * rz;

        float mx = fxrz * X + (float)IMG_W * 0.5f;
        float my = (float)IMG_H * 0.5f - fxrz * Y;

        float s0 = scl[g*3+0], s1 = scl[g*3+1], s2 = scl[g*3+2];
        float smax2 = fmaxf(fmaxf(s0*s0, s1*s1), s2*s2);  // = lmax(cov3d)
        float Xr = X * rz, Yr = Y * rz;
        float J2 = fxrz*fxrz * (1.0f + Xr*Xr + Yr*Yr);    // = lmax(J J^T)
        float rb = CULL_K * sqrtf(smax2 * J2 + 1e-5f);    // >= K*sqrt(max_eig)

        bool visible = (depth > NEAR_P) && (depth < FAR_P);
        s_cull[g] = make_float4(mx,
                                visible ? my : 1e30f,
                                visible ? rb : 0.0f,
                                visible ? -depth : INFINITY);
    }
    __syncthreads();

    // ---------------- P2: pre-cull + ballot compaction --------------------
    const int g0 = 2*tid, g1 = g0 + 1;
    float4 cr0 = s_cull[g0];
    float4 cr1 = s_cull[g1];
    bool p0 = (fabsf(cr0.y - yf) <= cr0.z) &
              (cr0.x >= x0f - cr0.z) & (cr0.x <= x0f + 63.0f + cr0.z);
    bool p1 = (fabsf(cr1.y - yf) <= cr1.z) &
              (cr1.x >= x0f - cr1.z) & (cr1.x <= x0f + 63.0f + cr1.z);

    unsigned long long m0 = __ballot(p0);
    unsigned long long m1 = __ballot(p1);
    const int lane = tid & 63;
    const int wv   = tid >> 6;
    unsigned long long lt = (1ull << lane) - 1ull;

    if (lane == 0) s_wtot[wv] = __popcll(m0) + __popcll(m1);
    __syncthreads();
    if (tid == 0) {
        int acc = 0;
        for (int i = 0; i < 4; ++i) { s_woff[i] = acc; acc += s_wtot[i]; }
        s_M = acc;
        s_Mf = 0;
    }
    __syncthreads();
    int basep = s_woff[wv] + __popcll(m0 & lt) + __popcll(m1 & lt);
    if (p0) { s_list[basep] = (unsigned short)g0; s_key2[basep] = cr0.w; }
    if (p1) { int p = basep + (p0 ? 1 : 0);
              s_list[p] = (unsigned short)g1; s_key2[p] = cr1.w; }
    const int M = s_M;
    if (tid < 4) s_key2[M + tid] = INFINITY;   // pad for float4 rank loop
    __syncthreads();

    // ---------------- P3: stable rank-sort of pre-survivors ---------------
    {
        const int Mp4 = (M + 3) >> 2;
        for (int t = tid; t < M; t += TPB) {
            float k = s_key2[t];
            int r = 0;
            for (int j4 = 0; j4 < Mp4; ++j4) {
                float4 kv = s_key4[j4];
                int j = 4*j4;
                r += (int)((kv.x < k) | ((kv.x == k) & (j     < t)));
                r += (int)((kv.y < k) | ((kv.y == k) & (j + 1 < t)));
                r += (int)((kv.z < k) | ((kv.z == k) & (j + 2 < t)));
                r += (int)((kv.w < k) | ((kv.w == k) & (j + 3 < t)));
            }
            s_order[r] = s_list[t];
        }
    }
    __syncthreads();

    // ------- P4: full preprocess of sorted survivors (two half-passes) ----
    for (int half = 0; half < 2; ++half) {
        if (half == 1 && M <= TPB) break;      // block-uniform
        const int t = half * TPB + tid;
        bool qp = false;
        float4 rec0 = make_float4(0,0,0,0), rec1 = make_float4(0,0,0,0);
        float bcol = 0.0f;
        if (t < M) {
            const int g = s_order[t];

            float qw = rot[g*4+0], qx = rot[g*4+1], qy = rot[g*4+2], qz = rot[g*4+3];
            float rn = __frsqrt_rn(qw*qw + qx*qx + qy*qy + qz*qz);
            qw *= rn; qx *= rn; qy *= rn; qz *= rn;
            float R00 = 1.f - 2.f*(qy*qy + qz*qz);
            float R01 = 2.f*(qx*qy - qw*qz);
            float R02 = 2.f*(qx*qz + qw*qy);
            float R10 = 2.f*(qx*qy + qw*qz);
            float R11 = 1.f - 2.f*(qx*qx + qz*qz);
            float R12 = 2.f*(qy*qz - qw*qx);
            float R20 = 2.f*(qx*qz - qw*qy);
            float R21 = 2.f*(qy*qz + qw*qx);
            float R22 = 1.f - 2.f*(qx*qx + qy*qy);

            float s0 = scl[g*3+0], s1 = scl[g*3+1], s2 = scl[g*3+2];
            float q0 = s0*s0, q1 = s1*s1, q2 = s2*s2;
            float C00 = R00*R00*q0 + R01*R01*q1 + R02*R02*q2;
            float C01 = R00*R10*q0 + R01*R11*q1 + R02*R12*q2;
            float C02 = R00*R20*q0 + R01*R21*q1 + R02*R22*q2;
            float C11 = R10*R10*q0 + R11*R11*q1 + R12*R12*q2;
            float C12 = R10*R20*q0 + R11*R21*q1 + R12*R22*q2;
            float C22 = R20*R20*q0 + R21*R21*q1 + R22*R22*q2;

            float px = pos[g*3+0], py = pos[g*3+1], pz = pos[g*3+2];
            float X = W00*px + W01*py + W02*pz + t0;
            float Y = W10*px + W11*py + W12*pz + t1;
            float Z = W20*px + W21*py + W22*pz + t2;

            float zs = fmaxf(Z, NEAR_P);
            float rz = __fdividef(1.0f, zs);
            float fxrz = fx * rz;

            float mx = fxrz * X + (float)IMG_W * 0.5f;
            float my = (float)IMG_H * 0.5f - fxrz * Y;

            float j02 = -fxrz * X * rz;
            float j12 = -fxrz * Y * rz;
            float T00 = fxrz*W00 + j02*W20;
            float T01 = fxrz*W01 + j02*W21;
            float T02 = fxrz*W02 + j02*W22;
            float T10 = fxrz*W10 + j12*W20;
            float T11 = fxrz*W11 + j12*W21;
            float T12 = fxrz*W12 + j12*W22;

            float u0 = C00*T00 + C01*T01 + C02*T02;
            float u1 = C01*T00 + C11*T01 + C12*T02;
            float u2 = C02*T00 + C12*T01 + C22*T02;
            float v0 = C00*T10 + C01*T11 + C02*T12;
            float v1 = C01*T10 + C11*T11 + C12*T12;
            float v2 = C02*T10 + C12*T11 + C22*T12;
            float a    = T00*u0 + T01*u1 + T02*u2;
            float bcov = 0.5f * ((T00*v0 + T01*v1 + T02*v2) + (T10*u0 + T11*u1 + T12*u2));
            float c    = T10*v0 + T11*v1 + T12*v2;

            float mean_e = 0.5f * (a + c);
            float disc = sqrtf(fmaxf(0.25f*(a - c)*(a - c) + bcov*bcov, 0.0f));
            float min_eig = mean_e - disc;
            float eps = (min_eig <= 0.0f) ? (fabsf(min_eig) + 1e-6f) : 0.0f;
            a += eps; c += eps;
            float max_eig = mean_e + eps + disc;

            float det  = fmaxf(a*c - bcov*bcov, 1e-12f);
            float rdet = __fdividef(1.0f, det);
            float ca = c * rdet, cbv = -bcov * rdet, cc = a * rdet;
            float op = __fdividef(1.0f, 1.0f + __expf(-opa[g]));

            float rk = CULL_K * sqrtf(fmaxf(max_eig, 1e-6f));
            qp = (fabsf(my - yf) <= rk) &
                 (mx >= x0f - rk) & (mx <= x0f + 63.0f + rk);

            rec0 = make_float4(-0.5f*ca, -cbv, -0.5f*cc, mx);
            rec1 = make_float4(my, op, col[g*3+0], col[g*3+1]);
            bcol = col[g*3+2];
        }
        unsigned long long mq = __ballot(qp);
        if (lane == 0) s_wtot[wv] = __popcll(mq);
        __syncthreads();
        if (tid == 0) {
            int acc = s_Mf;
            for (int i = 0; i < 4; ++i) { s_woff[i] = acc; acc += s_wtot[i]; }
            s_Mf = acc;
        }
        __syncthreads();
        int p = s_woff[wv] + __popcll(mq & lt);
        if (qp) { s_rec0[p] = rec0; s_rec1[p] = rec1; s_bcol[p] = bcol; }
    }
    __syncthreads();

    // ---------------- P5: chunked composite (direct indexing) -------------
    const int Mf = s_Mf;
    const int qn = (Mf + CHUNKS - 1) / CHUNKS;
    const int lpix  = tid & 63;
    const int chunk = tid >> 6;
    int start = chunk * qn; if (start > Mf) start = Mf;
    int end   = start + qn; if (end > Mf) end = Mf;

    const float fxp = x0f + (float)lpix;

    float Tr = 1.0f, ar = 0.0f, ag = 0.0f, abv = 0.0f;
    for (int i = start; i < end; ++i) {
        float4 r0 = s_rec0[i];
        float4 r1 = s_rec1[i];
        float  bc = s_bcol[i];
        float dx = fxp - r0.w;
        float dy = yf  - r1.x;
        float qv = (r0.x*dx)*dx + (r0.y*dx)*dy + (r0.z*dy)*dy; // = -0.5*q
        float G = __expf(fminf(qv, 0.0f));
        float alpha = fminf(r1.y * G, ALPHA_MAX);
        float wgt = alpha * Tr;
        ar  += wgt * r1.z;
        ag  += wgt * r1.w;
        abv += wgt * bc;
        Tr  *= (1.0f - alpha);
    }
    s_part[chunk][lpix] = make_float4(ar, ag, abv, Tr);
    __syncthreads();

    if (chunk == 0) {
        float4 c0 = s_part[0][lpix], c1 = s_part[1][lpix];
        float4 c2 = s_part[2][lpix], c3 = s_part[3][lpix];
        float T0 = c0.w, T01 = T0*c1.w, T012 = T01*c2.w, Tall = T012*c3.w;
        float r  = c0.x + T0*c1.x + T01*c2.x + T012*c3.x;
        float gc = c0.y + T0*c1.y + T01*c2.y + T012*c3.y;
        float bb = c0.z + T0*c1.z + T01*c2.z + T012*c3.z;
        s_out[3*lpix+0] = r  + Tall * bg[0];
        s_out[3*lpix+1] = gc + Tall * bg[1];
        s_out[3*lpix+2] = bb + Tall * bg[2];
    }
    __syncthreads();
    if (tid < PIX*3)
        out[b * (PIX*3) + tid] = s_out[tid];
}

extern "C" void kernel_launch(void* const* d_in, const int* in_sizes, int n_in,
                              void* d_out, int out_size, void* d_ws, size_t ws_size,
                              hipStream_t stream) {
    const float* pos = (const float*)d_in[0];
    const float* scl = (const float*)d_in[1];
    const float* rot = (const float*)d_in[2];
    const float* opa = (const float*)d_in[3];
    const float* col = (const float*)d_in[4];
    const float* vm  = (const float*)d_in[5];
    const float* bgp = (const float*)d_in[6];
    const int*   fov = (const int*)d_in[7];

    float* out = (float*)d_out;

    gs_fused<<<(IMG_H * IMG_W) / PIX, TPB, 0, stream>>>(
        pos, scl, rot, opa, col, vm, fov, bgp, out);
}